// Round 4
// baseline (147.230 us; speedup 1.0000x reference)
//
#include <hip/hip_runtime.h>
#include <math.h>

#define EPS 1e-6f
#define INVLN2 1.4426950408889634f    // 1/ln(2)
#define TWOINVLN2 2.8853900817779268f // 2/ln(2)

typedef float f32x4 __attribute__((ext_vector_type(4)));

// Native-instruction wrappers: v_log_f32 (log2), v_exp_f32 (exp2), v_rcp_f32, v_med3_f32
__device__ __forceinline__ float log2_hw(float x) { return __builtin_amdgcn_logf(x); }
__device__ __forceinline__ float exp2_hw(float x) { return __builtin_amdgcn_exp2f(x); }
__device__ __forceinline__ float rcp_hw(float x)  { return __builtin_amdgcn_rcpf(x); }
__device__ __forceinline__ float med3_hw(float x, float lo, float hi) {
    return __builtin_amdgcn_fmed3f(x, lo, hi);
}

// logit in log2 units: log2(p) - log2(1-p)  ( = logit(p)/ln2 )
__device__ __forceinline__ float logit_l2(float p) {
    float pc = med3_hw(p, EPS, 1.0f - EPS);
    return log2_hw(pc) - log2_hw(1.0f - pc);
}

// One point through the MLP. Weights pre-scaled:
//   w1d = 2*W1, b1s = b1*2/ln2   (so exp(2*pre) = exp2(w1d.zl + b1s))
//   w2s = W2/ln2, b2s = b2/ln2   (so exp(s_nat) = exp2(w2s.h + b2s))
__device__ __forceinline__ void point_eval(
    float p0, float p1, float p2,
    const float w1d[8][3], const float b1s[8],
    const float w2s[3][8], const float b2s[3],
    float& prob, float& a0o, float& a1o, float& a2o)
{
    float zl0 = logit_l2(p0);
    float zl1 = logit_l2(p1);
    float zl2 = logit_l2(p2);

    float s0 = b2s[0], s1 = b2s[1], s2 = b2s[2];
    #pragma unroll
    for (int j = 0; j < 8; ++j) {
        float arg = fmaf(w1d[j][0], zl0,
                    fmaf(w1d[j][1], zl1,
                    fmaf(w1d[j][2], zl2, b1s[j])));
        float E = exp2_hw(arg);                 // = exp(2*pre)
        float r = rcp_hw(E + 1.0f);
        float h = fmaf(-2.0f, r, 1.0f);         // tanh(pre)
        s0 = fmaf(w2s[0][j], h, s0);
        s1 = fmaf(w2s[1][j], h, s1);
        s2 = fmaf(w2s[2][j], h, s2);
    }

    // exp2 of log2-scaled logits == exp of natural logits; softmax exact.
    float e0 = exp2_hw(s0);
    float e1 = exp2_hw(s1);
    float e2 = exp2_hw(s2);
    float rden = rcp_hw(e0 + e1 + e2);
    float a0 = e0 * rden, a1 = e1 * rden, a2 = e2 * rden;

    float fl2 = fmaf(a0, zl0, fmaf(a1, zl1, a2 * zl2)); // fused_logit/ln2
    prob = rcp_hw(1.0f + exp2_hw(-fl2));
    a0o = a0; a1o = a1; a2o = a2;
}

__global__ __launch_bounds__(256) void attn_fusion_kernel(
    const float* __restrict__ p,
    const float* __restrict__ W1,
    const float* __restrict__ b1,
    const float* __restrict__ W2,
    const float* __restrict__ b2,
    float* __restrict__ out_prob,   // [B]
    float* __restrict__ out_a,      // [B,3]
    int ngroups)                    // B/8 groups of 8 points
{
    int t = blockIdx.x * blockDim.x + threadIdx.x;
    if (t >= ngroups) return;

    // Wave-uniform weight loads (constant indices -> SGPRs), pre-scaled.
    float w1d[8][3], b1s[8], w2s[3][8], b2s[3];
    #pragma unroll
    for (int j = 0; j < 8; ++j) {
        #pragma unroll
        for (int k = 0; k < 3; ++k) w1d[j][k] = 2.0f * W1[j * 3 + k];
        b1s[j] = b1[j] * TWOINVLN2;
    }
    #pragma unroll
    for (int k = 0; k < 3; ++k) {
        #pragma unroll
        for (int j = 0; j < 8; ++j) w2s[k][j] = W2[k * 8 + j] * INVLN2;
        b2s[k] = b2[k] * INVLN2;
    }

    // 8 points = 24 floats = 6 f32x4 nontemporal loads, issued up front.
    const f32x4* pv = reinterpret_cast<const f32x4*>(p) + (size_t)t * 6;
    f32x4 v[6];
    #pragma unroll
    for (int i = 0; i < 6; ++i) v[i] = __builtin_nontemporal_load(pv + i);

    float in[24];
    #pragma unroll
    for (int i = 0; i < 6; ++i) {
        in[i * 4 + 0] = v[i].x;
        in[i * 4 + 1] = v[i].y;
        in[i * 4 + 2] = v[i].z;
        in[i * 4 + 3] = v[i].w;
    }

    float probs[8];
    float av[24];

    #pragma unroll
    for (int q = 0; q < 8; ++q) {
        point_eval(in[q * 3 + 0], in[q * 3 + 1], in[q * 3 + 2],
                   w1d, b1s, w2s, b2s,
                   probs[q], av[q * 3 + 0], av[q * 3 + 1], av[q * 3 + 2]);
    }

    f32x4* po = reinterpret_cast<f32x4*>(out_prob) + (size_t)t * 2;
    f32x4 pr0 = {probs[0], probs[1], probs[2], probs[3]};
    f32x4 pr1 = {probs[4], probs[5], probs[6], probs[7]};
    __builtin_nontemporal_store(pr0, po + 0);
    __builtin_nontemporal_store(pr1, po + 1);

    f32x4* ao = reinterpret_cast<f32x4*>(out_a) + (size_t)t * 6;
    #pragma unroll
    for (int i = 0; i < 6; ++i) {
        f32x4 w = {av[i * 4 + 0], av[i * 4 + 1], av[i * 4 + 2], av[i * 4 + 3]};
        __builtin_nontemporal_store(w, ao + i);
    }
}

// Scalar tail kernel for B % 8 != 0 (not hit at B=8388608, kept for safety).
__global__ void attn_fusion_tail(
    const float* __restrict__ p,
    const float* __restrict__ W1,
    const float* __restrict__ b1,
    const float* __restrict__ W2,
    const float* __restrict__ b2,
    float* __restrict__ out_prob,
    float* __restrict__ out_a,
    int start, int B)
{
    int i = start + blockIdx.x * blockDim.x + threadIdx.x;
    if (i >= B) return;

    float w1d[8][3], b1s[8], w2s[3][8], b2s[3];
    #pragma unroll
    for (int j = 0; j < 8; ++j) {
        #pragma unroll
        for (int k = 0; k < 3; ++k) w1d[j][k] = 2.0f * W1[j * 3 + k];
        b1s[j] = b1[j] * TWOINVLN2;
    }
    #pragma unroll
    for (int k = 0; k < 3; ++k) {
        #pragma unroll
        for (int j = 0; j < 8; ++j) w2s[k][j] = W2[k * 8 + j] * INVLN2;
        b2s[k] = b2[k] * INVLN2;
    }

    float prob, a0, a1, a2;
    point_eval(p[(size_t)i * 3 + 0], p[(size_t)i * 3 + 1], p[(size_t)i * 3 + 2],
               w1d, b1s, w2s, b2s, prob, a0, a1, a2);
    out_prob[i] = prob;
    out_a[(size_t)i * 3 + 0] = a0;
    out_a[(size_t)i * 3 + 1] = a1;
    out_a[(size_t)i * 3 + 2] = a2;
}

extern "C" void kernel_launch(void* const* d_in, const int* in_sizes, int n_in,
                              void* d_out, int out_size, void* d_ws, size_t ws_size,
                              hipStream_t stream) {
    const float* p  = (const float*)d_in[0];
    const float* W1 = (const float*)d_in[1];
    const float* b1 = (const float*)d_in[2];
    const float* W2 = (const float*)d_in[3];
    const float* b2 = (const float*)d_in[4];

    int B = in_sizes[0] / 3;
    float* out_prob = (float*)d_out;        // [B]
    float* out_a    = (float*)d_out + B;    // [B,3]

    int ngroups = B / 8;
    if (ngroups > 0) {
        int block = 256;
        int grid = (ngroups + block - 1) / block;
        attn_fusion_kernel<<<grid, block, 0, stream>>>(
            p, W1, b1, W2, b2, out_prob, out_a, ngroups);
    }
    int tail = B - ngroups * 8;
    if (tail > 0) {
        attn_fusion_tail<<<1, 64, 0, stream>>>(
            p, W1, b1, W2, b2, out_prob, out_a, ngroups * 8, B);
    }
}

// Round 5
// 44.744 us; speedup vs baseline: 3.2905x; 3.2905x over previous
//
#include <hip/hip_runtime.h>
#include <math.h>

#define EPS 1e-6f
#define INVLN2 1.4426950408889634f    // 1/ln(2)
#define TWOINVLN2 2.8853900817779268f // 2/ln(2)

typedef float f32x4 __attribute__((ext_vector_type(4)));

// Native-instruction wrappers: v_log_f32 (log2), v_exp_f32 (exp2), v_rcp_f32, v_med3_f32
__device__ __forceinline__ float log2_hw(float x) { return __builtin_amdgcn_logf(x); }
__device__ __forceinline__ float exp2_hw(float x) { return __builtin_amdgcn_exp2f(x); }
__device__ __forceinline__ float rcp_hw(float x)  { return __builtin_amdgcn_rcpf(x); }
__device__ __forceinline__ float med3_hw(float x, float lo, float hi) {
    return __builtin_amdgcn_fmed3f(x, lo, hi);
}

// Padded float4 index: +1 float4 per 8 → breaks the mod-8 bank-conflict classes
// for BOTH the unit-stride phase (f(l)=l) and the 3-per-thread phase (f(t)=3t+k).
__device__ __forceinline__ int padi(int i) { return i + (i >> 3); }

// logit in log2 units: log2(p) - log2(1-p)  ( = logit(p)/ln2 )
__device__ __forceinline__ float logit_l2(float p) {
    float pc = med3_hw(p, EPS, 1.0f - EPS);
    return log2_hw(pc) - log2_hw(1.0f - pc);
}

// One point through the MLP. Weights pre-scaled:
//   w1d = 2*W1, b1s = b1*2/ln2   (so exp(2*pre) = exp2(w1d.zl + b1s))
//   w2s = W2/ln2, b2s = b2/ln2   (so exp(s_nat) = exp2(w2s.h + b2s))
__device__ __forceinline__ void point_eval(
    float p0, float p1, float p2,
    const float w1d[8][3], const float b1s[8],
    const float w2s[3][8], const float b2s[3],
    float& prob, float& a0o, float& a1o, float& a2o)
{
    float zl0 = logit_l2(p0);
    float zl1 = logit_l2(p1);
    float zl2 = logit_l2(p2);

    float s0 = b2s[0], s1 = b2s[1], s2 = b2s[2];
    #pragma unroll
    for (int j = 0; j < 8; ++j) {
        float arg = fmaf(w1d[j][0], zl0,
                    fmaf(w1d[j][1], zl1,
                    fmaf(w1d[j][2], zl2, b1s[j])));
        float E = exp2_hw(arg);                 // = exp(2*pre)
        float r = rcp_hw(E + 1.0f);
        float h = fmaf(-2.0f, r, 1.0f);         // tanh(pre)
        s0 = fmaf(w2s[0][j], h, s0);
        s1 = fmaf(w2s[1][j], h, s1);
        s2 = fmaf(w2s[2][j], h, s2);
    }

    // exp2 of log2-scaled logits == exp of natural logits; softmax exact.
    float e0 = exp2_hw(s0);
    float e1 = exp2_hw(s1);
    float e2 = exp2_hw(s2);
    float rden = rcp_hw(e0 + e1 + e2);
    float a0 = e0 * rden, a1 = e1 * rden, a2 = e2 * rden;

    float fl2 = fmaf(a0, zl0, fmaf(a1, zl1, a2 * zl2)); // fused_logit/ln2
    prob = rcp_hw(1.0f + exp2_hw(-fl2));
    a0o = a0; a1o = a1; a2o = a2;
}

// Block = 256 threads, 1024 points, LDS-staged coalesced I/O.
__global__ __launch_bounds__(256) void attn_fusion_kernel(
    const float* __restrict__ p,
    const float* __restrict__ W1,
    const float* __restrict__ b1,
    const float* __restrict__ W2,
    const float* __restrict__ b2,
    float* __restrict__ out_prob,   // [B]
    float* __restrict__ out_a)      // [B,3]
{
    __shared__ f32x4 lds4[864];     // 768 float4 + 96 pad = 13.8 KB

    int tid = threadIdx.x;
    size_t g = (size_t)blockIdx.x * 768;   // float4 base of this block's 1024 points

    // Wave-uniform weight loads (constant indices -> SGPRs), pre-scaled.
    float w1d[8][3], b1s[8], w2s[3][8], b2s[3];
    #pragma unroll
    for (int j = 0; j < 8; ++j) {
        #pragma unroll
        for (int k = 0; k < 3; ++k) w1d[j][k] = 2.0f * W1[j * 3 + k];
        b1s[j] = b1[j] * TWOINVLN2;
    }
    #pragma unroll
    for (int k = 0; k < 3; ++k) {
        #pragma unroll
        for (int j = 0; j < 8; ++j) w2s[k][j] = W2[k * 8 + j] * INVLN2;
        b2s[k] = b2[k] * INVLN2;
    }

    // Phase 1: unit-stride coalesced load -> LDS (padded).
    const f32x4* p4 = reinterpret_cast<const f32x4*>(p);
    #pragma unroll
    for (int k = 0; k < 3; ++k) {
        int i = tid + 256 * k;
        lds4[padi(i)] = __builtin_nontemporal_load(p4 + g + i);
    }
    __syncthreads();

    // Phase 2: each thread pulls its 4 points (3 conflict-free b128 reads).
    float in[12];
    #pragma unroll
    for (int k = 0; k < 3; ++k) {
        f32x4 v = lds4[padi(3 * tid + k)];
        in[k * 4 + 0] = v.x;
        in[k * 4 + 1] = v.y;
        in[k * 4 + 2] = v.z;
        in[k * 4 + 3] = v.w;
    }

    float probs[4];
    float av[12];
    #pragma unroll
    for (int q = 0; q < 4; ++q) {
        point_eval(in[q * 3 + 0], in[q * 3 + 1], in[q * 3 + 2],
                   w1d, b1s, w2s, b2s,
                   probs[q], av[q * 3 + 0], av[q * 3 + 1], av[q * 3 + 2]);
    }

    // Phase 3: a-values back to LDS (same slots this thread read — no barrier
    // needed before: location 3t+k is only ever read in phase 2 by thread t).
    #pragma unroll
    for (int k = 0; k < 3; ++k) {
        f32x4 w = {av[k * 4 + 0], av[k * 4 + 1], av[k * 4 + 2], av[k * 4 + 3]};
        lds4[padi(3 * tid + k)] = w;
    }
    __syncthreads();

    // Phase 4: unit-stride coalesced stores.
    f32x4* a4 = reinterpret_cast<f32x4*>(out_a);
    #pragma unroll
    for (int k = 0; k < 3; ++k) {
        int i = tid + 256 * k;
        __builtin_nontemporal_store(lds4[padi(i)], a4 + g + i);
    }

    // prob: 1 float4 per thread, naturally coalesced.
    f32x4 pr = {probs[0], probs[1], probs[2], probs[3]};
    __builtin_nontemporal_store(
        pr, reinterpret_cast<f32x4*>(out_prob) + (size_t)blockIdx.x * 256 + tid);
}

// Scalar tail kernel for B % 1024 != 0 (not hit at B=8388608, kept for safety).
__global__ void attn_fusion_tail(
    const float* __restrict__ p,
    const float* __restrict__ W1,
    const float* __restrict__ b1,
    const float* __restrict__ W2,
    const float* __restrict__ b2,
    float* __restrict__ out_prob,
    float* __restrict__ out_a,
    int start, int B)
{
    int i = start + blockIdx.x * blockDim.x + threadIdx.x;
    if (i >= B) return;

    float w1d[8][3], b1s[8], w2s[3][8], b2s[3];
    #pragma unroll
    for (int j = 0; j < 8; ++j) {
        #pragma unroll
        for (int k = 0; k < 3; ++k) w1d[j][k] = 2.0f * W1[j * 3 + k];
        b1s[j] = b1[j] * TWOINVLN2;
    }
    #pragma unroll
    for (int k = 0; k < 3; ++k) {
        #pragma unroll
        for (int j = 0; j < 8; ++j) w2s[k][j] = W2[k * 8 + j] * INVLN2;
        b2s[k] = b2[k] * INVLN2;
    }

    float prob, a0, a1, a2;
    point_eval(p[(size_t)i * 3 + 0], p[(size_t)i * 3 + 1], p[(size_t)i * 3 + 2],
               w1d, b1s, w2s, b2s, prob, a0, a1, a2);
    out_prob[i] = prob;
    out_a[(size_t)i * 3 + 0] = a0;
    out_a[(size_t)i * 3 + 1] = a1;
    out_a[(size_t)i * 3 + 2] = a2;
}

extern "C" void kernel_launch(void* const* d_in, const int* in_sizes, int n_in,
                              void* d_out, int out_size, void* d_ws, size_t ws_size,
                              hipStream_t stream) {
    const float* p  = (const float*)d_in[0];
    const float* W1 = (const float*)d_in[1];
    const float* b1 = (const float*)d_in[2];
    const float* W2 = (const float*)d_in[3];
    const float* b2 = (const float*)d_in[4];

    int B = in_sizes[0] / 3;
    float* out_prob = (float*)d_out;        // [B]
    float* out_a    = (float*)d_out + B;    // [B,3]

    int nblocks = B / 1024;                 // full blocks of 1024 points
    if (nblocks > 0) {
        attn_fusion_kernel<<<nblocks, 256, 0, stream>>>(
            p, W1, b1, W2, b2, out_prob, out_a);
    }
    int start = nblocks * 1024;
    int tail = B - start;
    if (tail > 0) {
        int tb = (tail + 255) / 256;
        attn_fusion_tail<<<tb, 256, 0, stream>>>(
            p, W1, b1, W2, b2, out_prob, out_a, start, B);
    }
}

// Round 6
// 41.951 us; speedup vs baseline: 3.5096x; 1.0666x over previous
//
#include <hip/hip_runtime.h>
#include <math.h>

#define EPS 1e-6f
#define INVLN2 1.4426950408889634f    // 1/ln(2)
#define TWOINVLN2 2.8853900817779268f // 2/ln(2)

typedef float f32x4 __attribute__((ext_vector_type(4)));
typedef float f32x2 __attribute__((ext_vector_type(2)));

// Native-instruction wrappers: v_log_f32 (log2), v_exp_f32 (exp2), v_rcp_f32
__device__ __forceinline__ float log2_hw(float x) { return __builtin_amdgcn_logf(x); }
__device__ __forceinline__ float exp2_hw(float x) { return __builtin_amdgcn_exp2f(x); }
__device__ __forceinline__ float rcp_hw(float x)  { return __builtin_amdgcn_rcpf(x); }

// f32x2 helpers: packed ops map to v_pk_{fma,add,mul}_f32; trans stay scalar.
__device__ __forceinline__ f32x2 bc2(float s)      { f32x2 v = {s, s}; return v; }
__device__ __forceinline__ f32x2 fma2(f32x2 a, f32x2 b, f32x2 c) {
    return __builtin_elementwise_fma(a, b, c);
}
__device__ __forceinline__ f32x2 exp2_v2(f32x2 x) {
    f32x2 r = {exp2_hw(x.x), exp2_hw(x.y)}; return r;
}
__device__ __forceinline__ f32x2 log2_v2(f32x2 x) {
    f32x2 r = {log2_hw(x.x), log2_hw(x.y)}; return r;
}
__device__ __forceinline__ f32x2 rcp_v2(f32x2 x) {
    f32x2 r = {rcp_hw(x.x), rcp_hw(x.y)}; return r;
}

// Two points through the MLP, packed in f32x2 lanes.
// Pre-scaled params:
//   w1d = 2*W1, b1s = b1*2/ln2    (exp(2*pre) = exp2(w1d.zl + b1s))
//   w2n = -2*W2/ln2               (h=1-2r folded into W2)
//   cc  = (b2 + sum_j W2[:,j])/ln2
__device__ __forceinline__ void point_eval2(
    f32x2 q0, f32x2 q1, f32x2 q2,
    const float w1d[8][3], const float b1s[8],
    const float w2n[3][8], const float cc[3],
    f32x2& prob, f32x2& a0, f32x2& a1, f32x2& a2)
{
    // clamp + logit in log2 units: zl = log2(pc) - log2(1-pc)
    const f32x2 lo = bc2(EPS), hi = bc2(1.0f - EPS), one = bc2(1.0f);
    f32x2 pc0 = __builtin_elementwise_min(__builtin_elementwise_max(q0, lo), hi);
    f32x2 pc1 = __builtin_elementwise_min(__builtin_elementwise_max(q1, lo), hi);
    f32x2 pc2 = __builtin_elementwise_min(__builtin_elementwise_max(q2, lo), hi);
    f32x2 zl0 = log2_v2(pc0) - log2_v2(one - pc0);
    f32x2 zl1 = log2_v2(pc1) - log2_v2(one - pc1);
    f32x2 zl2 = log2_v2(pc2) - log2_v2(one - pc2);

    f32x2 s0 = bc2(cc[0]), s1 = bc2(cc[1]), s2 = bc2(cc[2]);
    #pragma unroll
    for (int j = 0; j < 8; ++j) {
        f32x2 arg = fma2(bc2(w1d[j][0]), zl0,
                    fma2(bc2(w1d[j][1]), zl1,
                    fma2(bc2(w1d[j][2]), zl2, bc2(b1s[j]))));
        f32x2 r = rcp_v2(exp2_v2(arg) + one);   // 1/(exp(2*pre)+1)
        s0 = fma2(bc2(w2n[0][j]), r, s0);
        s1 = fma2(bc2(w2n[1][j]), r, s1);
        s2 = fma2(bc2(w2n[2][j]), r, s2);
    }

    // softmax (s already in log2 units; exp2 == exp of natural logits)
    f32x2 e0 = exp2_v2(s0);
    f32x2 e1 = exp2_v2(s1);
    f32x2 e2 = exp2_v2(s2);
    f32x2 rden = rcp_v2(e0 + e1 + e2);
    a0 = e0 * rden; a1 = e1 * rden; a2 = e2 * rden;

    f32x2 fl2 = fma2(a0, zl0, fma2(a1, zl1, a2 * zl2)); // fused_logit/ln2
    prob = rcp_v2(one + exp2_v2(-fl2));
}

__global__ __launch_bounds__(256) void attn_fusion_kernel(
    const float* __restrict__ p,
    const float* __restrict__ W1,
    const float* __restrict__ b1,
    const float* __restrict__ W2,
    const float* __restrict__ b2,
    float* __restrict__ out_prob,   // [B]
    float* __restrict__ out_a,      // [B,3]
    int ngroups)                    // B/4 groups of 4 points
{
    int t = blockIdx.x * blockDim.x + threadIdx.x;
    if (t >= ngroups) return;

    // Wave-uniform weight loads (constant indices -> SGPRs), pre-scaled.
    float w1d[8][3], b1s[8], w2n[3][8], cc[3];
    #pragma unroll
    for (int j = 0; j < 8; ++j) {
        #pragma unroll
        for (int k = 0; k < 3; ++k) w1d[j][k] = 2.0f * W1[j * 3 + k];
        b1s[j] = b1[j] * TWOINVLN2;
    }
    #pragma unroll
    for (int k = 0; k < 3; ++k) {
        float sum = 0.0f;
        #pragma unroll
        for (int j = 0; j < 8; ++j) {
            float w2s = W2[k * 8 + j] * INVLN2;
            w2n[k][j] = -2.0f * w2s;
            sum += w2s;
        }
        cc[k] = b2[k] * INVLN2 + sum;
    }

    // 4 points = 12 floats = 3 float4 loads (same pattern as the 43us R2 kernel).
    const f32x4* pv = reinterpret_cast<const f32x4*>(p) + (size_t)t * 3;
    f32x4 v0 = pv[0];
    f32x4 v1 = pv[1];
    f32x4 v2 = pv[2];
    float in[12] = {v0.x, v0.y, v0.z, v0.w,
                    v1.x, v1.y, v1.z, v1.w,
                    v2.x, v2.y, v2.z, v2.w};

    // Pair A = points 0,1 ; pair B = points 2,3 (packed in f32x2 lanes).
    f32x2 qA0 = {in[0], in[3]}, qA1 = {in[1], in[4]}, qA2 = {in[2], in[5]};
    f32x2 qB0 = {in[6], in[9]}, qB1 = {in[7], in[10]}, qB2 = {in[8], in[11]};

    f32x2 prA, aA0, aA1, aA2;
    f32x2 prB, aB0, aB1, aB2;
    point_eval2(qA0, qA1, qA2, w1d, b1s, w2n, cc, prA, aA0, aA1, aA2);
    point_eval2(qB0, qB1, qB2, w1d, b1s, w2n, cc, prB, aB0, aB1, aB2);

    f32x4 pr = {prA.x, prA.y, prB.x, prB.y};
    reinterpret_cast<f32x4*>(out_prob)[t] = pr;

    f32x4* ao = reinterpret_cast<f32x4*>(out_a) + (size_t)t * 3;
    f32x4 o0 = {aA0.x, aA1.x, aA2.x, aA0.y};
    f32x4 o1 = {aA1.y, aA2.y, aB0.x, aB1.x};
    f32x4 o2 = {aB2.x, aB0.y, aB1.y, aB2.y};
    ao[0] = o0;
    ao[1] = o1;
    ao[2] = o2;
}

// Scalar tail kernel for B % 4 != 0 (not hit at B=8388608, kept for safety).
__global__ void attn_fusion_tail(
    const float* __restrict__ p,
    const float* __restrict__ W1,
    const float* __restrict__ b1,
    const float* __restrict__ W2,
    const float* __restrict__ b2,
    float* __restrict__ out_prob,
    float* __restrict__ out_a,
    int start, int B)
{
    int i = start + blockIdx.x * blockDim.x + threadIdx.x;
    if (i >= B) return;

    float zl[3];
    #pragma unroll
    for (int k = 0; k < 3; ++k) {
        float pc = fminf(fmaxf(p[(size_t)i * 3 + k], EPS), 1.0f - EPS);
        zl[k] = log2_hw(pc) - log2_hw(1.0f - pc);
    }

    float s[3];
    #pragma unroll
    for (int k = 0; k < 3; ++k) {
        float sum = 0.0f;
        #pragma unroll
        for (int j = 0; j < 8; ++j) sum += W2[k * 8 + j] * INVLN2;
        s[k] = b2[k] * INVLN2 + sum;
    }
    #pragma unroll
    for (int j = 0; j < 8; ++j) {
        float arg = b1[j] * TWOINVLN2;
        #pragma unroll
        for (int k = 0; k < 3; ++k) arg = fmaf(2.0f * W1[j * 3 + k], zl[k], arg);
        float r = rcp_hw(exp2_hw(arg) + 1.0f);
        #pragma unroll
        for (int k = 0; k < 3; ++k) s[k] = fmaf(-2.0f * W2[k * 8 + j] * INVLN2, r, s[k]);
    }
    float e0 = exp2_hw(s[0]), e1 = exp2_hw(s[1]), e2 = exp2_hw(s[2]);
    float rden = rcp_hw(e0 + e1 + e2);
    float a0 = e0 * rden, a1 = e1 * rden, a2 = e2 * rden;
    out_a[(size_t)i * 3 + 0] = a0;
    out_a[(size_t)i * 3 + 1] = a1;
    out_a[(size_t)i * 3 + 2] = a2;
    float fl2 = fmaf(a0, zl[0], fmaf(a1, zl[1], a2 * zl[2]));
    out_prob[i] = rcp_hw(1.0f + exp2_hw(-fl2));
}

extern "C" void kernel_launch(void* const* d_in, const int* in_sizes, int n_in,
                              void* d_out, int out_size, void* d_ws, size_t ws_size,
                              hipStream_t stream) {
    const float* p  = (const float*)d_in[0];
    const float* W1 = (const float*)d_in[1];
    const float* b1 = (const float*)d_in[2];
    const float* W2 = (const float*)d_in[3];
    const float* b2 = (const float*)d_in[4];

    int B = in_sizes[0] / 3;
    float* out_prob = (float*)d_out;        // [B]
    float* out_a    = (float*)d_out + B;    // [B,3]

    int ngroups = B / 4;
    if (ngroups > 0) {
        int block = 256;
        int grid = (ngroups + block - 1) / block;
        attn_fusion_kernel<<<grid, block, 0, stream>>>(
            p, W1, b1, W2, b2, out_prob, out_a, ngroups);
    }
    int tail = B - ngroups * 4;
    if (tail > 0) {
        attn_fusion_tail<<<1, 64, 0, stream>>>(
            p, W1, b1, W2, b2, out_prob, out_a, ngroups * 4, B);
    }
}